// Round 8
// baseline (1256.761 us; speedup 1.0000x reference)
//
#include <hip/hip_runtime.h>
#include <stdint.h>
#include <math.h>

// EncoderSRNN: T=127 steps, BSZ=32 items, HDIM=256, SDIM=128, SSZ=128.
// One WG (1024 threads = 16 waves) per item. Weights are NOT register-resident
// (R2-R7: every residency scheme spilled or serialized); they are STREAMED from
// the packed L2-hot blob each step with coalesced uint4 loads (384 B/thread/step,
// 384 KB/CU/step, same addresses every step -> L2 hits). ws4/out deliberately
// NOT __restrict__ so LICM cannot hoist the loop-invariant weight loads into a
// persistent (spilling) array. 16 waves hide L2+LDS latency. Stack f32 in LDS,
// column-parallel conflict-free update. buf recurrence collapsed to a 128-coeff
// scalar window over precomputed E2H (emb@We2h^T), emb_W[PAD]==0.

#define T_STEPS 127

// flat f32 output offsets (outputs, hid, stack, acts, top_elems)
#define OUT_OFF   0
#define HID_OFF   1040384
#define STACK_OFF 1048576
#define ACTS_OFF  1572864
#define TE_OFF    1580992

// ws layout (uint4 granularity for weight blobs), 1024-thread mappings:
//  uint4 [0,16384):      W1 = s2h (t_<512) / h2h (t_>=512), per-thread 16 uint4
//  uint4 [16384,20480):  W3 = h2s, per-thread 4 uint4
//  uint4 [20480,24576):  W2 = s2u, per-thread 4 uint4
//  uint4 [24576,32768):  W0 = We2h^T packed [k-chunk][j] for prep_e2h
//  uint  [131072,393216): E2H f16-pairs per item: [b][r2*256+j] = (row2r2,row2r2+1)
#define E2H_OFF_U 131072

typedef _Float16 h2 __attribute__((ext_vector_type(2)));

__device__ __forceinline__ unsigned packh2(float a, float b){
  h2 v; v.x = (_Float16)a; v.y = (_Float16)b;
  return __builtin_bit_cast(unsigned, v);
}
__device__ __forceinline__ float h2loF(unsigned u){ h2 v = __builtin_bit_cast(h2,u); return (float)v.x; }
__device__ __forceinline__ float h2hiF(unsigned u){ h2 v = __builtin_bit_cast(h2,u); return (float)v.y; }

#if __has_builtin(__builtin_amdgcn_fdot2)
__device__ __forceinline__ float fdot2(unsigned a, unsigned b, float c){
  return __builtin_amdgcn_fdot2(__builtin_bit_cast(h2,a), __builtin_bit_cast(h2,b), c, false);
}
#else
__device__ __forceinline__ float fdot2(unsigned a, unsigned b, float c){
  return c + h2loF(a)*h2loF(b) + h2hiF(a)*h2hiF(b);
}
#endif

// chunked (bank-staggered) layout for packed act vectors: logical uint u ->
// physical 12*(u>>3) + (u&7).  16 chunks x 12 uints = 192 uints.
#define CHOFF(u) (12*((u)>>3) + ((u)&7))

// ---------------- prep: pack all weights to f16 blobs ----------------
__global__ void prep_pack(const float* __restrict__ We2h, const float* __restrict__ Ws2h,
                          const float* __restrict__ Wh2h, const float* __restrict__ Wh2s,
                          const float* __restrict__ Ws2u, uint4* __restrict__ out4){
  int gid = blockIdx.x*256 + threadIdx.x;    // [0, 32768)
  const float* src;
  if (gid < 16384){                          // W1: i in [0,16), t in [0,1024)
    int i = gid >> 10, t_ = gid & 1023;
    const float* S = (t_ < 512) ? Ws2h : Wh2h;
    int r = t_ & 511, jp = r >> 2, ks = r & 3;
    int j = 2*jp + (i >> 3);
    int k0 = ks*64 + (i & 7)*8;
    src = S + j*256 + k0;
  } else if (gid < 20480){                   // W3 (h2s): i in [0,4)
    int l = gid - 16384, i = l >> 10, t_ = l & 1023;
    int jr = t_ >> 4, kb = t_ & 15;
    int j = 2*jr + (i >> 1);
    int k0 = kb*16 + (i & 1)*8;
    src = Wh2s + j*256 + k0;
  } else if (gid < 24576){                   // W2 (s2u)
    int l = gid - 20480, i = l >> 10, t_ = l & 1023;
    int jr = t_ >> 4, kb = t_ & 15;
    int j = 2*jr + (i >> 1);
    int k0 = kb*16 + (i & 1)*8;
    src = Ws2u + j*256 + k0;
  } else {                                   // W0: [k-chunk i8][j]
    int l = gid - 24576;
    int i8 = l >> 8, j = l & 255;
    src = We2h + j*256 + i8*8;
  }
  uint4 r4;
  r4.x = packh2(src[0], src[1]); r4.y = packh2(src[2], src[3]);
  r4.z = packh2(src[4], src[5]); r4.w = packh2(src[6], src[7]);
  out4[gid] = r4;
}

// ---------------- prep: E2H = emb @ We2h^T, f16 row-pairs ----------------
__global__ void prep_e2h(const int* __restrict__ inputs, const float* __restrict__ embW,
                         const uint4* __restrict__ w04, unsigned* __restrict__ e2hpk){
  __shared__ float emb[8][256];
  int tid = threadIdx.x;
  int r2 = blockIdx.x >> 3, bg = blockIdx.x & 7;
  for (int q=0;q<8;q++){
    int rr = q >> 2, bb = q & 3;
    int tok = inputs[(2*r2+rr)*32 + bg*4+bb];
    emb[q][tid] = embW[tok*256 + tid];
  }
  __syncthreads();
  float acc[8] = {0.f,0.f,0.f,0.f,0.f,0.f,0.f,0.f};
  for (int i8=0;i8<32;i8++){
    uint4 u = w04[i8*256 + tid];
    unsigned uu[4] = {u.x,u.y,u.z,u.w};
    #pragma unroll
    for (int c=0;c<4;c++){
      float lo = h2loF(uu[c]), hi = h2hiF(uu[c]);
      int k = i8*8 + c*2;
      #pragma unroll
      for (int q=0;q<8;q++)
        acc[q] += emb[q][k]*lo + emb[q][k+1]*hi;
    }
  }
  int base = (bg*4)*8192 + r2*256 + tid;
  #pragma unroll
  for (int bb=0;bb<4;bb++)
    e2hpk[base + bb*8192] = packh2(acc[bb], acc[4+bb]);  // (row 2r2, row 2r2+1)
}

// ---------------- main sequential kernel ----------------
__global__ __launch_bounds__(1024, 1)
void srnn_main(const uint4* ws4, const unsigned* wsu,            // NO restrict: blocks LICM
               const float* __restrict__ b_e2h, const float* __restrict__ b_s2h,
               const float* __restrict__ b_h2h, const float* __restrict__ Wh2i,
               const float* __restrict__ b_h2i, const float* __restrict__ b_h2s,
               const float* __restrict__ b_s2u, const float* __restrict__ empty_el,
               float* out)                                        // NO restrict
{
  __shared__ __align__(16) float    stk_s[128*128];     // stack f32, 64 KB, no pad
  __shared__ __align__(16) unsigned e2h_s[32*258];      // f16 pairs, stride 258
  __shared__ __align__(16) unsigned s_pk[192];          // tops f16, chunk-staggered
  __shared__ __align__(16) unsigned hid_pk[192];        // hid f16, chunk-staggered
  __shared__ __align__(16) float    pv_s[128], uv_s[128];
  __shared__ __align__(16) float    accih[256], acchp[256];
  __shared__ __align__(16) float    emptyf_s[128];
  __shared__ float    wbuf[2][192];
  __shared__ unsigned pkwc[32];
  __shared__ float    partsum[12];
  __shared__ float    pp_s, pq_s;

  const int tid = threadIdx.x;
  const int b   = blockIdx.x;
  const int aside = tid >> 9;           // phase A: 0=ih(s2h), 1=hp(h2h)
  const int ar  = tid & 511;
  const int ajp = ar >> 2;              // output pair 0..127
  const int aks = ar & 3;               // K-split 4 (K=64 each)
  const int jr  = tid >> 4;             // phase B output pair 0..63
  const int ksb = tid & 15;             // phase B K-split 16 (K=16 each)
  const int g   = tid >> 6;             // stack: wave id = row-group (8 rows)
  const int cp  = tid & 63;             // stack: column pair

  float bA0=0.f, bA1=0.f;
  if (aks==0){
    int j0 = 2*ajp;
    if (aside==0){ bA0 = b_e2h[j0]+b_s2h[j0]; bA1 = b_e2h[j0+1]+b_s2h[j0+1]; }
    else         { bA0 = b_h2h[j0];           bA1 = b_h2h[j0+1]; }
  }
  float bH0=0.f,bH1=0.f,bU0=0.f,bU1=0.f;
  if (ksb==0){ bH0=b_h2s[2*jr]; bH1=b_h2s[2*jr+1]; bU0=b_s2u[2*jr]; bU1=b_s2u[2*jr+1]; }
  float rW0=0.f,rW1=0.f,rW2=0.f;
  if (tid<256){ rW0=Wh2i[tid]; rW1=Wh2i[256+tid]; rW2=Wh2i[512+tid]; }
  const float bi0=b_h2i[0], bi1=b_h2i[1], bi2=b_h2i[2];

  // ---- init LDS state ----
  const unsigned* e2hg = wsu + E2H_OFF_U + b*8192;
  #pragma unroll
  for (int q=0;q<8;q++){
    int idx = q*1024 + tid;
    e2h_s[(idx>>8)*258 + (idx&255)] = e2hg[idx];
  }
  {
    float2 e2 = *(const float2*)&empty_el[2*cp];
    #pragma unroll
    for (int j=0;j<8;j++)
      *(float2*)&stk_s[(8*g+j)*128 + 2*cp] = e2;
  }
  if (tid < 128){
    emptyf_s[tid] = empty_el[tid];
    hid_pk[CHOFF(tid)] = 0u;
    int cu = tid & 63;
    s_pk[CHOFF(tid)] = packh2(empty_el[2*cu], empty_el[2*cu+1]);
  }
  if (tid < 192){ wbuf[0][tid] = (tid==64)?1.f:0.f; wbuf[1][tid]=0.f; }
  if (tid < 32)  pkwc[tid] = (tid==0)? packh2(1.f,0.f) : 0u;
  __syncthreads();

  int cur = 0;
  for (int t=0;t<T_STEPS;++t){
    // ============ Phase A: ihid (s2h + inp-window) & hid-pre (h2h) ============
    {
      const unsigned* act  = aside ? hid_pk : s_pk;
      const unsigned* actB = act + 48*aks;
      // stream this thread's 16 weight uint4 (same addresses every step -> L2-hot)
      uint4 Wv[16];
      #pragma unroll
      for (int i=0;i<16;i++) Wv[i] = ws4[i*1024 + tid];
      float x0 = 0.f, x1 = 0.f;
      if (aside==0){
        #pragma unroll
        for (int q=0;q<8;q++){
          int r2 = aks*8 + q;
          unsigned cw = pkwc[r2];
          uint2 e = *(const uint2*)&e2h_s[r2*258 + 2*ajp];
          x0 = fdot2(cw, e.x, x0);
          x1 = fdot2(cw, e.y, x1);
        }
      }
      #pragma unroll
      for (int i=0;i<8;i++){
        uint4 A  = *(const uint4*)(actB + 12*(i>>1) + 4*(i&1));
        uint4 Wa = Wv[i], Wb = Wv[8+i];
        x0 = fdot2(A.x,Wa.x,x0); x0 = fdot2(A.y,Wa.y,x0);
        x0 = fdot2(A.z,Wa.z,x0); x0 = fdot2(A.w,Wa.w,x0);
        x1 = fdot2(A.x,Wb.x,x1); x1 = fdot2(A.y,Wb.y,x1);
        x1 = fdot2(A.z,Wb.z,x1); x1 = fdot2(A.w,Wb.w,x1);
      }
      x0 += __shfl_xor(x0,1); x0 += __shfl_xor(x0,2);
      x1 += __shfl_xor(x1,1); x1 += __shfl_xor(x1,2);
      if (aks==0){
        float* dst = aside ? acchp : accih;
        *(float2*)&dst[2*ajp] = make_float2(x0 + bA0, x1 + bA1);
      }
    }
    __syncthreads();                                   // B1

    // ---- hid update + inst partials ----
    if (tid < 128){
      float2 ih2 = *(const float2*)&accih[2*tid];
      float2 hp2 = *(const float2*)&acchp[2*tid];
      float hn0 = fmaxf(ih2.x+hp2.x, 0.f);
      float hn1 = fmaxf(ih2.y+hp2.y, 0.f);
      hid_pk[CHOFF(tid)] = packh2(hn0,hn1);
      *(float2*)&out[OUT_OFF + t*8192 + b*256 + 2*tid] = make_float2(hn0,hn1);
      if (t==T_STEPS-1) *(float2*)&out[HID_OFF + b*256 + 2*tid] = make_float2(hn0,hn1);
    }
    if (tid < 256){
      float v = accih[tid];
      float p0=v*rW0, p1=v*rW1, p2=v*rW2;
      #pragma unroll
      for (int o=32;o>=1;o>>=1){ p0+=__shfl_xor(p0,o); p1+=__shfl_xor(p1,o); p2+=__shfl_xor(p2,o); }
      if ((tid&63)==0){ int w=tid>>6; partsum[w*3]=p0; partsum[w*3+1]=p1; partsum[w*3+2]=p2; }
    }
    __syncthreads();                                   // B2

    // ---- softmax/gating on wave 0 ----
    if (tid < 64){
      float i0 = bi0+partsum[0]+partsum[3]+partsum[6]+partsum[9];
      float i1 = bi1+partsum[1]+partsum[4]+partsum[7]+partsum[10];
      float gi = bi2+partsum[2]+partsum[5]+partsum[8]+partsum[11];
      float mx = fmaxf(i0,i1);
      float e0 = expf(i0-mx), e1 = expf(i1-mx);
      float inv = 1.f/(e0+e1);
      float act0 = e0*inv, act1 = e1*inv;
      float gamma = 1.f + log1pf(expf(gi));
      float A0 = powf(act0,gamma), A1 = powf(act1,gamma);
      float sden = A0+A1+1e-16f;
      float ppv = A0/sden, pqv = A1/sden;
      if (tid==0){
        pp_s = ppv; pq_s = pqv;
        *(float2*)&out[ACTS_OFF + t*64 + b*2] = make_float2(ppv,pqv);
      }
    }

    // ============ Phase B: h2s (new hid) & s2u (old tops) ============
    {
      uint4 W3v[4], W2v[4];
      #pragma unroll
      for (int i=0;i<4;i++){ W3v[i] = ws4[16384 + i*1024 + tid];
                             W2v[i] = ws4[20480 + i*1024 + tid]; }
      const uint4* hptr = (const uint4*)(hid_pk + 12*ksb);
      const uint4* sptr = (const uint4*)(s_pk   + 12*ksb);
      uint4 H0 = hptr[0], H1 = hptr[1];
      uint4 S0 = sptr[0], S1 = sptr[1];
      float h0=0.f,h1=0.f,u0=0.f,u1=0.f;
      h0=fdot2(H0.x,W3v[0].x,h0); h0=fdot2(H0.y,W3v[0].y,h0); h0=fdot2(H0.z,W3v[0].z,h0); h0=fdot2(H0.w,W3v[0].w,h0);
      h0=fdot2(H1.x,W3v[1].x,h0); h0=fdot2(H1.y,W3v[1].y,h0); h0=fdot2(H1.z,W3v[1].z,h0); h0=fdot2(H1.w,W3v[1].w,h0);
      h1=fdot2(H0.x,W3v[2].x,h1); h1=fdot2(H0.y,W3v[2].y,h1); h1=fdot2(H0.z,W3v[2].z,h1); h1=fdot2(H0.w,W3v[2].w,h1);
      h1=fdot2(H1.x,W3v[3].x,h1); h1=fdot2(H1.y,W3v[3].y,h1); h1=fdot2(H1.z,W3v[3].z,h1); h1=fdot2(H1.w,W3v[3].w,h1);
      u0=fdot2(S0.x,W2v[0].x,u0); u0=fdot2(S0.y,W2v[0].y,u0); u0=fdot2(S0.z,W2v[0].z,u0); u0=fdot2(S0.w,W2v[0].w,u0);
      u0=fdot2(S1.x,W2v[1].x,u0); u0=fdot2(S1.y,W2v[1].y,u0); u0=fdot2(S1.z,W2v[1].z,u0); u0=fdot2(S1.w,W2v[1].w,u0);
      u1=fdot2(S0.x,W2v[2].x,u1); u1=fdot2(S0.y,W2v[2].y,u1); u1=fdot2(S0.z,W2v[2].z,u1); u1=fdot2(S0.w,W2v[2].w,u1);
      u1=fdot2(S1.x,W2v[3].x,u1); u1=fdot2(S1.y,W2v[3].y,u1); u1=fdot2(S1.z,W2v[3].z,u1); u1=fdot2(S1.w,W2v[3].w,u1);
      #pragma unroll
      for (int o=8;o>=1;o>>=1){
        h0+=__shfl_xor(h0,o); h1+=__shfl_xor(h1,o);
        u0+=__shfl_xor(u0,o); u1+=__shfl_xor(u1,o);
      }
      if (ksb==0){
        pv_s[2*jr]   = fmaxf(h0+bH0,0.f);
        pv_s[2*jr+1] = fmaxf(h1+bH1,0.f);
        uv_s[2*jr]   = fmaxf(u0+bU0,0.f);
        uv_s[2*jr+1] = fmaxf(u1+bU1,0.f);
      }
    }
    __syncthreads();                                   // B3
    const float pp = pp_s, pq = pq_s;

    // ============ Stack update: column-parallel, conflict-free ============
    {
      float2 w[10];                                    // rows 8g-1 .. 8g+8
      #pragma unroll
      for (int k=0;k<10;k++){
        int r = 8*g - 1 + k;
        if (r >= 0 && r <= 127)
          w[k] = *(const float2*)&stk_s[r*128 + 2*cp];
      }
      if (g == 15) w[9] = *(const float2*)&emptyf_s[2*cp];
      float2 pv2 = make_float2(0.f,0.f), uv2 = make_float2(0.f,0.f);
      if (g == 0){ pv2 = *(const float2*)&pv_s[2*cp]; uv2 = *(const float2*)&uv_s[2*cp]; }
      float2 nn[8];
      #pragma unroll
      for (int j=0;j<8;j++){
        nn[j].x = pp*w[j].x + pq*w[j+2].x;
        nn[j].y = pp*w[j].y + pq*w[j+2].y;
      }
      if (g == 0){
        nn[0].x = pp*pv2.x + pq*uv2.x;
        nn[0].y = pp*pv2.y + pq*uv2.y;
      }
      // coefficient recurrence for the collapsed buf + next-step packed pairs
      if (tid < 128){
        int k = 64+tid;
        wbuf[cur^1][k] = pp*wbuf[cur][k] + pq*wbuf[cur][k-1];
      } else if (tid < 160){
        int r2 = tid-128;
        int k1 = 65 + t - 2*r2;
        float wa = wbuf[cur][k1], wb2 = wbuf[cur][k1-1], wc2 = wbuf[cur][k1-2];
        pkwc[r2] = packh2(pp*wa+pq*wb2, pp*wb2+pq*wc2);
      }
      __syncthreads();                                 // S_e (all reads done)
      #pragma unroll
      for (int j=0;j<8;j++)
        *(float2*)&stk_s[(8*g+j)*128 + 2*cp] = nn[j];
      if (g == 0){
        *(float2*)&out[TE_OFF + t*4096 + b*128 + 2*cp] = nn[0];
        s_pk[CHOFF(cp)]      = packh2(nn[0].x, nn[0].y);
        s_pk[CHOFF(64+cp)]   = packh2(nn[1].x, nn[1].y);
      }
    }
    __syncthreads();                                   // S_f
    cur ^= 1;
  }

  // ---- final stack output ----
  #pragma unroll
  for (int j=0;j<8;j++){
    int r = 8*g + j;
    *(float2*)&out[STACK_OFF + b*16384 + r*128 + 2*cp] =
      *(const float2*)&stk_s[r*128 + 2*cp];
  }
}

extern "C" void kernel_launch(void* const* d_in, const int* in_sizes, int n_in,
                              void* d_out, int out_size, void* d_ws, size_t ws_size,
                              hipStream_t stream){
  const int*   inputs = (const int*)d_in[0];
  const float* embW   = (const float*)d_in[1];
  const float* We2h   = (const float*)d_in[2];
  const float* b_e2h  = (const float*)d_in[3];
  const float* Ws2h   = (const float*)d_in[4];
  const float* b_s2h  = (const float*)d_in[5];
  const float* Wh2h   = (const float*)d_in[6];
  const float* b_h2h  = (const float*)d_in[7];
  const float* Wh2i   = (const float*)d_in[8];
  const float* b_h2i  = (const float*)d_in[9];
  const float* Wh2s   = (const float*)d_in[10];
  const float* b_h2s  = (const float*)d_in[11];
  const float* Ws2u   = (const float*)d_in[12];
  const float* b_s2u  = (const float*)d_in[13];
  const float* empty  = (const float*)d_in[14];
  unsigned* wsu = (unsigned*)d_ws;

  prep_pack<<<dim3(128), dim3(256), 0, stream>>>(We2h, Ws2h, Wh2h, Wh2s, Ws2u, (uint4*)wsu);
  prep_e2h<<<dim3(256), dim3(256), 0, stream>>>(inputs, embW, ((const uint4*)wsu)+24576, wsu + E2H_OFF_U);
  srnn_main<<<dim3(32), dim3(1024), 0, stream>>>((const uint4*)wsu, (const unsigned*)wsu,
                                                 b_e2h, b_s2h, b_h2h, Wh2i, b_h2i,
                                                 b_h2s, b_s2u, empty, (float*)d_out);
}